// Round 6
// baseline (332.161 us; speedup 1.0000x reference)
//
#include <hip/hip_runtime.h>

typedef _Float16 half8  __attribute__((ext_vector_type(8)));
typedef _Float16 half4v __attribute__((ext_vector_type(4)));
typedef float    float4v __attribute__((ext_vector_type(4)));

#define N_ 4096
#define B_ 8
#define D_ 64
#define F_ 128

// ---------------- K1: pack adjacency to bitmask ----------------
__global__ __launch_bounds__(256) void pack_adj_kernel(const int* __restrict__ adj,
                                                       unsigned long long* __restrict__ bits) {
  int i = blockIdx.x * 256 + threadIdx.x;
  unsigned long long m = __ballot(adj[i] > 0);
  if ((threadIdx.x & 63) == 0) bits[i >> 6] = m;
}

// ---------------- K2: Wh = h @ W (LDS-tiled) + fused transpose ----------------
__global__ __launch_bounds__(256) void wh_kernel(const float* __restrict__ h,
                                                 const float* __restrict__ W,
                                                 _Float16* __restrict__ Wh16,
                                                 _Float16* __restrict__ WhT16) {
  __shared__ __align__(16) float    hs[64][132];   // h tile
  __shared__ __align__(16) _Float16 wt[64][132];   // W^T fp16
  __shared__ __align__(16) _Float16 otile[64][72]; // out tile for transpose
  const int t = threadIdx.x;
  const int rowbase = blockIdx.x * 64;
  const float4v* hg = (const float4v*)(h + (size_t)rowbase * F_);
#pragma unroll
  for (int k = 0; k < 8; ++k) {
    int i4 = t + k * 256;
    float4v v = hg[i4];
    int r = i4 >> 5, c4 = (i4 & 31) * 4;
    *(float4v*)&hs[r][c4] = v;
  }
#pragma unroll
  for (int k = 0; k < 8; ++k) {
    int i4 = t + k * 256;
    float4v v = ((const float4v*)W)[i4];
    int f = i4 >> 4, c4 = (i4 & 15) * 4;
    wt[c4 + 0][f] = (_Float16)v[0];
    wt[c4 + 1][f] = (_Float16)v[1];
    wt[c4 + 2][f] = (_Float16)v[2];
    wt[c4 + 3][f] = (_Float16)v[3];
  }
  __syncthreads();
  const int w = t >> 6, lane = t & 63;
  const int r0 = w * 16;
  float acc[16];
#pragma unroll
  for (int i = 0; i < 16; ++i) acc[i] = 0.f;
#pragma unroll 4
  for (int f4 = 0; f4 < 32; ++f4) {
    half4v wv = *(half4v*)&wt[lane][f4 * 4];
    float w0 = (float)wv[0], w1 = (float)wv[1], w2 = (float)wv[2], w3 = (float)wv[3];
#pragma unroll
    for (int i = 0; i < 16; ++i) {
      float4v hv = *(float4v*)&hs[r0 + i][f4 * 4]; // wave-uniform -> broadcast
      acc[i] += hv[0] * w0 + hv[1] * w1 + hv[2] * w2 + hv[3] * w3;
    }
  }
#pragma unroll
  for (int i = 0; i < 16; ++i) {
    _Float16 hv = (_Float16)acc[i];
    Wh16[(size_t)(rowbase + r0 + i) * D_ + lane] = hv;
    otile[r0 + i][lane] = hv;
  }
  __syncthreads();
  // transposed store: WhT[b][d][n]
  const int dl = t >> 2, k0t = (t & 3) * 16;
  half8 o0, o1;
#pragma unroll
  for (int i = 0; i < 8; ++i) o0[i] = otile[k0t + i][dl];
#pragma unroll
  for (int i = 0; i < 8; ++i) o1[i] = otile[k0t + 8 + i][dl];
  const int b = rowbase >> 12, n0 = rowbase & 4095;
  _Float16* dst = WhT16 + ((size_t)(b * D_ + dl)) * N_ + n0 + k0t;
  *(half8*)dst       = o0;
  *(half8*)(dst + 8) = o1;
}

// ---------------- K3: flash attention + ELU ----------------
// Block = 512 thr = 8 waves: 2 q-chunks(16 rows) x 4 KV-quarters (split-K 4-way).
// Grid 1024 -> 3 blocks/CU (24 waves). K staged in LDS (XOR swizzle); V read
// directly from L2-resident WhT (overlaps softmax). Softmax in log2 domain.
__global__ __launch_bounds__(512, 6) void attn_kernel(
    const unsigned long long* __restrict__ bits,
    const _Float16* __restrict__ Wh,
    const _Float16* __restrict__ WhT,
    float* __restrict__ out) {
  __shared__ __align__(16) char lds[49152];  // [0,32K) Kst[4] | [32K,48K) P[8]; epi: Ob[128][64]+mlb
  const int tid  = threadIdx.x;
  const int w    = tid >> 6;
  const int lane = tid & 63;
  const int g    = lane >> 4;
  const int c    = lane & 15;
  const int qi   = w & 1;
  const int s    = w >> 1;                       // 0..3 KV-quarter
  const int bid  = blockIdx.x;
  const int b    = bid >> 7;
  const int q0b  = (bid & 127) * 32;
  const int q0w  = q0b + qi * 16;

  const _Float16* Whb  = Wh  + (size_t)b * N_ * D_;
  const _Float16* WhTb = WhT + (size_t)b * D_ * N_;
  _Float16* Kst = (_Float16*)(lds + s * 8192);
  char* Pb = lds + 32768 + w * 2048;

  // staging: s-group = 2 waves (128 thr), 4 half8-slots each; linear LDS dest,
  // inverse-swizzled global source (slot ^= row&7)
  const int li = qi * 64 + lane;
  int er[4], es[4];
#pragma unroll
  for (int i = 0; i < 4; ++i) {
    int e = li + i * 128;
    er[i] = e >> 3;
    es[i] = (e & 7) ^ (er[i] & 7);
  }

  half8 qf[2];
#pragma unroll
  for (int ds = 0; ds < 2; ++ds) {
    half8 v = *(const half8*)(Whb + (size_t)(q0w + c) * D_ + ds * 32 + g * 8);
    qf[ds] = v * (_Float16)0.18033688f;          // 1/8 * log2(e): scores in log2 domain
  }

  float4v o_acc[4];
#pragma unroll
  for (int d = 0; d < 4; ++d) o_acc[d] = (float4v){0.f, 0.f, 0.f, 0.f};
  float mrow = -1e30f, lrow = 0.f;

  const unsigned long long* bq = bits + (size_t)(q0w + c) * 64 + s * 16;

  // prefetch tile 0
  int k0n = (s * 16) * 64;
  half8 kpre[4];
#pragma unroll
  for (int i = 0; i < 4; ++i)
    kpre[i] = *(const half8*)(Whb + (size_t)(k0n + er[i]) * D_ + es[i] * 8);
  unsigned long long bw = bq[0];

  for (int t = 0; t < 16; ++t) {
    __syncthreads();                             // previous tile's K reads done
#pragma unroll
    for (int i = 0; i < 4; ++i)
      *(half8*)(Kst + (li + i * 128) * 8) = kpre[i];
    __syncthreads();                             // stage visible

    const int kc = (s * 16 + t) * 64;            // current tile key base
    const int t1 = (t + 1 < 16) ? t + 1 : 15;
    k0n = (s * 16 + t1) * 64;
#pragma unroll
    for (int i = 0; i < 4; ++i)
      kpre[i] = *(const half8*)(Whb + (size_t)(k0n + er[i]) * D_ + es[i] * 8);
    unsigned long long bwn = bq[t1];

    // ---- QK^T (S^T: rows=k, cols=q), scores in log2 domain ----
    float4v sac[4];
#pragma unroll
    for (int st = 0; st < 4; ++st) {
      const _Float16* kr = Kst + (st * 16 + c) * 64;
      half8 kf0 = *(const half8*)(kr + ((g       ^ (c & 7)) * 8));
      half8 kf1 = *(const half8*)(kr + (((g + 4) ^ (c & 7)) * 8));
      float4v z = (float4v){0.f, 0.f, 0.f, 0.f};
      z = __builtin_amdgcn_mfma_f32_16x16x32_f16(kf0, qf[0], z, 0, 0, 0);
      z = __builtin_amdgcn_mfma_f32_16x16x32_f16(kf1, qf[1], z, 0, 0, 0);
      sac[st] = z;
    }

    // ---- mask to -1e9 BEFORE max (fp16 P needs P_max = 1) ----
    float tmax = -1e30f;
#pragma unroll
    for (int st = 0; st < 4; ++st) {
      unsigned wb = (unsigned)(bw >> (st * 16 + g * 4));
#pragma unroll
      for (int j = 0; j < 4; ++j) {
        float v = (wb & (1u << j)) ? sac[st][j] : -1e9f;
        sac[st][j] = v;
        tmax = fmaxf(tmax, v);
      }
    }
    tmax = fmaxf(tmax, __shfl_xor(tmax, 16));
    tmax = fmaxf(tmax, __shfl_xor(tmax, 32));

    float mnew  = fmaxf(mrow, tmax);
    float alpha = exp2f(mrow - mnew);
    mrow = mnew;
    lrow *= alpha;
#pragma unroll
    for (int j = 0; j < 4; ++j) {
      float aj = __shfl(alpha, (lane & 48) | (g * 4 + j));
#pragma unroll
      for (int d = 0; d < 4; ++d) o_acc[d][j] *= aj;
    }

    // ---- P = exp2(s-m), pack fp16, LDS write ----
#pragma unroll
    for (int st = 0; st < 4; ++st) {
      float p0 = exp2f(sac[st][0] - mrow);
      float p1 = exp2f(sac[st][1] - mrow);
      float p2 = exp2f(sac[st][2] - mrow);
      float p3 = exp2f(sac[st][3] - mrow);
      lrow += (p0 + p1) + (p2 + p3);
      uint2 pr;
      pr.x = __builtin_bit_cast(unsigned, __builtin_amdgcn_cvt_pkrtz(p0, p1));
      pr.y = __builtin_bit_cast(unsigned, __builtin_amdgcn_cvt_pkrtz(p2, p3));
      const int cell = st * 2 + (g >> 1);
      *(uint2*)(Pb + (cell * 16 + c) * 16 + (g & 1) * 8) = pr;
    }

    // ---- PV: O += P * V (V direct from L2-resident WhT) ----
#pragma unroll
    for (int ks = 0; ks < 2; ++ks) {
      half8 af = *(const half8*)(Pb + ((ks * 4 + g) * 16 + c) * 16);
#pragma unroll
      for (int d = 0; d < 4; ++d) {
        half8 vf = *(const half8*)(WhTb + (size_t)(d * 16 + c) * N_ + kc + ks * 32 + g * 8);
        o_acc[d] = __builtin_amdgcn_mfma_f32_16x16x32_f16(af, vf, o_acc[d], 0, 0, 0);
      }
    }
    bw = bwn;
  }

  // ---- epilogue: reduce l, merge 4 KV-quarter partials, ELU, store ----
  lrow += __shfl_xor(lrow, 16);
  lrow += __shfl_xor(lrow, 32);
  __syncthreads();                               // stage+P dead; reuse LDS
  float* Ob = (float*)lds;                       // [128][64] fp32 (wave-slot rows)
#pragma unroll
  for (int d = 0; d < 4; ++d)
#pragma unroll
    for (int j = 0; j < 4; ++j)
      Ob[(w * 16 + g * 4 + j) * 64 + d * 16 + c] = o_acc[d][j];
  float2* mlb = (float2*)(lds + 32768);
  if (g == 0) mlb[w * 16 + c] = make_float2(mrow, lrow);
  __syncthreads();

#pragma unroll
  for (int it = 0; it < 4; ++it) {
    int idx = tid + it * 512;                    // 32 rows x 64 cols
    int r = idx >> 6, col = idx & 63;
    int qq = r >> 4, rl = r & 15;
    float2 ml[4];
    float mm = -1e30f;
#pragma unroll
    for (int p = 0; p < 4; ++p) {
      ml[p] = mlb[(p * 2 + qq) * 16 + rl];
      mm = fmaxf(mm, ml[p].x);
    }
    float l = 0.f, o = 0.f;
#pragma unroll
    for (int p = 0; p < 4; ++p) {
      float a = exp2f(ml[p].x - mm);
      l += a * ml[p].y;
      o += a * Ob[((p * 2 + qq) * 16 + rl) * 64 + col];
    }
    float x = o / l;
    x = x > 0.f ? x : (__expf(x) - 1.f);
    out[((size_t)b * N_ + q0b + r) * D_ + col] = x;
  }
}

extern "C" void kernel_launch(void* const* d_in, const int* in_sizes, int n_in,
                              void* d_out, int out_size, void* d_ws, size_t ws_size,
                              hipStream_t stream) {
  const float* h = (const float*)d_in[0];
  const float* W = (const float*)d_in[1];
  const int* adj = (const int*)d_in[2];
  float* out = (float*)d_out;

  char* ws = (char*)d_ws;
  unsigned long long* bits = (unsigned long long*)ws;      // 2 MiB
  _Float16* Wh16  = (_Float16*)(ws + (2u << 20));          // 4 MiB
  _Float16* WhT16 = (_Float16*)(ws + (6u << 20));          // 4 MiB

  hipLaunchKernelGGL(pack_adj_kernel, dim3((N_ * N_) / 256), dim3(256), 0, stream, adj, bits);
  hipLaunchKernelGGL(wh_kernel,   dim3((B_ * N_) / 64), dim3(256), 0, stream, h, W, Wh16, WhT16);
  hipLaunchKernelGGL(attn_kernel, dim3(B_ * (N_ / 32)), dim3(512), 0, stream, bits, Wh16, WhT16, out);
}

// Round 7
// 204.597 us; speedup vs baseline: 1.6235x; 1.6235x over previous
//
#include <hip/hip_runtime.h>

typedef _Float16 half8  __attribute__((ext_vector_type(8)));
typedef _Float16 half4v __attribute__((ext_vector_type(4)));
typedef float    float4v __attribute__((ext_vector_type(4)));

#define N_ 4096
#define B_ 8
#define D_ 64
#define F_ 128

// ---------------- K1: pack adjacency to bitmask (int4 = 16B/lane) ----------------
__global__ __launch_bounds__(256) void pack_adj_kernel(const int4* __restrict__ adj4,
                                                       unsigned long long* __restrict__ bits) {
  __shared__ unsigned char nib[256];
  const int t = threadIdx.x;
  int4 v = adj4[(size_t)blockIdx.x * 256 + t];
  unsigned n = (v.x > 0 ? 1u : 0u) | (v.y > 0 ? 2u : 0u) |
               (v.z > 0 ? 4u : 0u) | (v.w > 0 ? 8u : 0u);
  nib[t] = (unsigned char)n;
  __syncthreads();
  if (t < 16) {
    const unsigned char* p = &nib[t * 16];
    unsigned long long wv = 0;
#pragma unroll
    for (int i = 0; i < 16; ++i) wv |= (unsigned long long)p[i] << (4 * i);
    bits[(size_t)blockIdx.x * 16 + t] = wv;
  }
}

// ---------------- K2: Wh = h @ W (LDS-tiled) + fused transpose ----------------
__global__ __launch_bounds__(256) void wh_kernel(const float* __restrict__ h,
                                                 const float* __restrict__ W,
                                                 _Float16* __restrict__ Wh16,
                                                 _Float16* __restrict__ WhT16) {
  __shared__ __align__(16) float    hs[64][132];
  __shared__ __align__(16) _Float16 wt[64][132];
  __shared__ __align__(16) _Float16 otile[64][72];
  const int t = threadIdx.x;
  const int rowbase = blockIdx.x * 64;
  const float4v* hg = (const float4v*)(h + (size_t)rowbase * F_);
#pragma unroll
  for (int k = 0; k < 8; ++k) {
    int i4 = t + k * 256;
    float4v v = hg[i4];
    int r = i4 >> 5, c4 = (i4 & 31) * 4;
    *(float4v*)&hs[r][c4] = v;
  }
#pragma unroll
  for (int k = 0; k < 8; ++k) {
    int i4 = t + k * 256;
    float4v v = ((const float4v*)W)[i4];
    int f = i4 >> 4, c4 = (i4 & 15) * 4;
    wt[c4 + 0][f] = (_Float16)v[0];
    wt[c4 + 1][f] = (_Float16)v[1];
    wt[c4 + 2][f] = (_Float16)v[2];
    wt[c4 + 3][f] = (_Float16)v[3];
  }
  __syncthreads();
  const int w = t >> 6, lane = t & 63;
  const int r0 = w * 16;
  float acc[16];
#pragma unroll
  for (int i = 0; i < 16; ++i) acc[i] = 0.f;
#pragma unroll 4
  for (int f4 = 0; f4 < 32; ++f4) {
    half4v wv = *(half4v*)&wt[lane][f4 * 4];
    float w0 = (float)wv[0], w1 = (float)wv[1], w2 = (float)wv[2], w3 = (float)wv[3];
#pragma unroll
    for (int i = 0; i < 16; ++i) {
      float4v hv = *(float4v*)&hs[r0 + i][f4 * 4]; // wave-uniform -> broadcast
      acc[i] += hv[0] * w0 + hv[1] * w1 + hv[2] * w2 + hv[3] * w3;
    }
  }
#pragma unroll
  for (int i = 0; i < 16; ++i) {
    _Float16 hv = (_Float16)acc[i];
    Wh16[(size_t)(rowbase + r0 + i) * D_ + lane] = hv;
    otile[r0 + i][lane] = hv;
  }
  __syncthreads();
  const int dl = t >> 2, k0t = (t & 3) * 16;
  half8 o0, o1;
#pragma unroll
  for (int i = 0; i < 8; ++i) o0[i] = otile[k0t + i][dl];
#pragma unroll
  for (int i = 0; i < 8; ++i) o1[i] = otile[k0t + 8 + i][dl];
  const int b = rowbase >> 12, n0 = rowbase & 4095;
  _Float16* dst = WhT16 + ((size_t)(b * D_ + dl)) * N_ + n0 + k0t;
  *(half8*)dst       = o0;
  *(half8*)(dst + 8) = o1;
}

// ---------------- K3: flash attention + ELU ----------------
// Round-5 structure (verified 92.7us) + K/V DOUBLE-BUFFER (1 barrier/tile)
// + exp2-domain softmax. 512 thr = 8 waves: 4 q-chunks(16 rows) x 2 KV-halves.
// LDS 80KB: Kst[s][d] 32K | Vst[s][d] 32K | P[8] 16K. V STAYS LDS-STAGED
// (round 6 proved V-direct is 2.2x worse: dependent global loads in PV chain).
__global__ __launch_bounds__(512, 4) void attn_kernel(
    const unsigned long long* __restrict__ bits,
    const _Float16* __restrict__ Wh,
    const _Float16* __restrict__ WhT,
    float* __restrict__ out) {
  __shared__ __align__(16) char lds[81920];
  const int tid  = threadIdx.x;
  const int w    = tid >> 6;
  const int lane = tid & 63;
  const int g    = lane >> 4;
  const int c    = lane & 15;
  const int qi   = w & 3;
  const int s    = w >> 2;
  const int bid  = blockIdx.x;
  const int b    = bid >> 6;
  const int q0b  = (bid & 63) * 64;
  const int q0w  = q0b + qi * 16;

  const _Float16* Whb  = Wh  + (size_t)b * N_ * D_;
  const _Float16* WhTb = WhT + (size_t)b * D_ * N_;
  char* Kbase = lds + s * 16384;           // two 8K buffers
  char* Vbase = lds + 32768 + s * 16384;   // two 8K buffers
  char* Pb    = lds + 65536 + w * 2048;

  // staging map: e = (qi*2+i)*64 + lane ; row=e>>3, slot'=e&7, src slot = slot'^(row&7)
  const int e0  = (qi * 2 + 0) * 64 + lane;
  const int e1  = (qi * 2 + 1) * 64 + lane;
  const int r0e = e0 >> 3, s0e = (e0 & 7) ^ (r0e & 7);
  const int r1e = e1 >> 3, s1e = (e1 & 7) ^ (r1e & 7);

  half8 qf[2];
#pragma unroll
  for (int ds = 0; ds < 2; ++ds) {
    half8 v = *(const half8*)(Whb + (size_t)(q0w + c) * D_ + ds * 32 + g * 8);
    qf[ds] = v * (_Float16)0.18033688f;          // (1/8)*log2(e): log2-domain scores
  }

  float4v o_acc[4];
#pragma unroll
  for (int d = 0; d < 4; ++d) o_acc[d] = (float4v){0.f, 0.f, 0.f, 0.f};
  float mrow = -1e30f, lrow = 0.f;

  const unsigned long long* bq = bits + (size_t)(q0w + c) * 64 + s * 32;

  // prefetch + stage tile 0 into buffer 0
  int k0n = (s * 32) * 64;
  half8 ka = *(const half8*)(Whb + (size_t)(k0n + r0e) * D_ + s0e * 8);
  half8 kb = *(const half8*)(Whb + (size_t)(k0n + r1e) * D_ + s1e * 8);
  half8 va = *(const half8*)(WhTb + (size_t)r0e * N_ + k0n + s0e * 8);
  half8 vb = *(const half8*)(WhTb + (size_t)r1e * N_ + k0n + s1e * 8);
  unsigned long long bw = bq[0];
  *(half8*)(Kbase + e0 * 16) = ka;
  *(half8*)(Kbase + e1 * 16) = kb;
  *(half8*)(Vbase + e0 * 16) = va;
  *(half8*)(Vbase + e1 * 16) = vb;
  __syncthreads();

  for (int t = 0; t < 32; ++t) {
    const int cur = (t & 1) * 8192, nxt = 8192 - cur;
    const _Float16* Kc = (const _Float16*)(Kbase + cur);
    const _Float16* Vc = (const _Float16*)(Vbase + cur);

    // issue next tile's global loads (latency hides under this tile's compute)
    const int t1 = (t + 1 < 32) ? t + 1 : 31;
    k0n = (s * 32 + t1) * 64;
    ka = *(const half8*)(Whb + (size_t)(k0n + r0e) * D_ + s0e * 8);
    kb = *(const half8*)(Whb + (size_t)(k0n + r1e) * D_ + s1e * 8);
    va = *(const half8*)(WhTb + (size_t)r0e * N_ + k0n + s0e * 8);
    vb = *(const half8*)(WhTb + (size_t)r1e * N_ + k0n + s1e * 8);
    unsigned long long bwn = bq[t1];

    // ---- QK^T (S^T: rows=k, cols=q) ----
    float4v sac[4];
#pragma unroll
    for (int st = 0; st < 4; ++st) {
      const _Float16* kr = Kc + (st * 16 + c) * 64;
      half8 kf0 = *(const half8*)(kr + ((g       ^ (c & 7)) * 8));
      half8 kf1 = *(const half8*)(kr + (((g + 4) ^ (c & 7)) * 8));
      float4v z = (float4v){0.f, 0.f, 0.f, 0.f};
      z = __builtin_amdgcn_mfma_f32_16x16x32_f16(kf0, qf[0], z, 0, 0, 0);
      z = __builtin_amdgcn_mfma_f32_16x16x32_f16(kf1, qf[1], z, 0, 0, 0);
      sac[st] = z;
    }

    // ---- mask to -1e9 BEFORE max (fp16 P needs P_max = 1) ----
    float tmax = -1e30f;
#pragma unroll
    for (int st = 0; st < 4; ++st) {
      unsigned wb = (unsigned)(bw >> (st * 16 + g * 4));
#pragma unroll
      for (int j = 0; j < 4; ++j) {
        float v = (wb & (1u << j)) ? sac[st][j] : -1e9f;
        sac[st][j] = v;
        tmax = fmaxf(tmax, v);
      }
    }
    tmax = fmaxf(tmax, __shfl_xor(tmax, 16));
    tmax = fmaxf(tmax, __shfl_xor(tmax, 32));

    float mnew  = fmaxf(mrow, tmax);
    float alpha = exp2f(mrow - mnew);
    mrow = mnew;
    lrow *= alpha;
#pragma unroll
    for (int j = 0; j < 4; ++j) {
      float aj = __shfl(alpha, (lane & 48) | (g * 4 + j));
#pragma unroll
      for (int d = 0; d < 4; ++d) o_acc[d][j] *= aj;
    }

    // ---- P = exp2(s-m), pack fp16, wave-private LDS write ----
#pragma unroll
    for (int st = 0; st < 4; ++st) {
      float p0 = exp2f(sac[st][0] - mrow);
      float p1 = exp2f(sac[st][1] - mrow);
      float p2 = exp2f(sac[st][2] - mrow);
      float p3 = exp2f(sac[st][3] - mrow);
      lrow += (p0 + p1) + (p2 + p3);
      uint2 pr;
      pr.x = __builtin_bit_cast(unsigned, __builtin_amdgcn_cvt_pkrtz(p0, p1));
      pr.y = __builtin_bit_cast(unsigned, __builtin_amdgcn_cvt_pkrtz(p2, p3));
      const int cell = st * 2 + (g >> 1);
      *(uint2*)(Pb + (cell * 16 + c) * 16 + (g & 1) * 8) = pr;
    }

    // ---- PV: O += P * V (V from LDS) ----
#pragma unroll
    for (int ks = 0; ks < 2; ++ks) {
      half8 af = *(const half8*)(Pb + ((ks * 4 + g) * 16 + c) * 16);
#pragma unroll
      for (int d = 0; d < 4; ++d) {
        const int vrow = d * 16 + c;
        half8 vf = *(const half8*)(Vc + vrow * 64 + (((ks * 4 + g) ^ (c & 7)) * 8));
        o_acc[d] = __builtin_amdgcn_mfma_f32_16x16x32_f16(af, vf, o_acc[d], 0, 0, 0);
      }
    }

    // ---- stage next tile into the other buffer ----
    *(half8*)(Kbase + nxt + e0 * 16) = ka;
    *(half8*)(Kbase + nxt + e1 * 16) = kb;
    *(half8*)(Vbase + nxt + e0 * 16) = va;
    *(half8*)(Vbase + nxt + e1 * 16) = vb;
    __syncthreads();                             // one barrier per tile
    bw = bwn;
  }

  // ---- epilogue: reduce l, merge the two KV-half partials, ELU, store ----
  lrow += __shfl_xor(lrow, 16);
  lrow += __shfl_xor(lrow, 32);
  __syncthreads();                               // all staging/P dead; reuse LDS
  float* Ob = (float*)lds;                       // [128][66] fp32
#pragma unroll
  for (int d = 0; d < 4; ++d)
#pragma unroll
    for (int j = 0; j < 4; ++j)
      Ob[(w * 16 + g * 4 + j) * 66 + d * 16 + c] = o_acc[d][j];
  float2* mlb = (float2*)(lds + 36864);
  if (g == 0) mlb[w * 16 + c] = make_float2(mrow, lrow);
  __syncthreads();

#pragma unroll
  for (int it = 0; it < 8; ++it) {
    int r   = w + it * 8;
    int col = lane;
    int qq = r >> 4, rl = r & 15;
    float2 ml0 = mlb[qq * 16 + rl];
    float2 ml1 = mlb[(qq + 4) * 16 + rl];
    float mm = fmaxf(ml0.x, ml1.x);
    float a0 = exp2f(ml0.x - mm);
    float a1 = exp2f(ml1.x - mm);
    float l  = a0 * ml0.y + a1 * ml1.y;
    float o  = a0 * Ob[(qq * 16 + rl) * 66 + col] + a1 * Ob[((qq + 4) * 16 + rl) * 66 + col];
    float x  = o / l;
    x = x > 0.f ? x : (__expf(x) - 1.f);
    out[((size_t)b * N_ + q0b + r) * D_ + col] = x;
  }
}

extern "C" void kernel_launch(void* const* d_in, const int* in_sizes, int n_in,
                              void* d_out, int out_size, void* d_ws, size_t ws_size,
                              hipStream_t stream) {
  const float* h = (const float*)d_in[0];
  const float* W = (const float*)d_in[1];
  const int* adj = (const int*)d_in[2];
  float* out = (float*)d_out;

  char* ws = (char*)d_ws;
  unsigned long long* bits = (unsigned long long*)ws;      // 2 MiB
  _Float16* Wh16  = (_Float16*)(ws + (2u << 20));          // 4 MiB
  _Float16* WhT16 = (_Float16*)(ws + (6u << 20));          // 4 MiB

  hipLaunchKernelGGL(pack_adj_kernel, dim3((N_ * N_) / 1024), dim3(256), 0, stream,
                     (const int4*)adj, bits);
  hipLaunchKernelGGL(wh_kernel,   dim3((B_ * N_) / 64), dim3(256), 0, stream, h, W, Wh16, WhT16);
  hipLaunchKernelGGL(attn_kernel, dim3(B_ * (N_ / 64)), dim3(512), 0, stream, bits, Wh16, WhT16, out);
}

// Round 8
// 191.867 us; speedup vs baseline: 1.7312x; 1.0663x over previous
//
#include <hip/hip_runtime.h>

typedef _Float16 half8  __attribute__((ext_vector_type(8)));
typedef float    float4v __attribute__((ext_vector_type(4)));

#define N_ 4096
#define B_ 8
#define D_ 64
#define F_ 128

// ---------------- K1: pack adjacency to bitmask (int4 = 16B/lane) ----------------
__global__ __launch_bounds__(256) void pack_adj_kernel(const int4* __restrict__ adj4,
                                                       unsigned long long* __restrict__ bits) {
  __shared__ unsigned char nib[256];
  const int t = threadIdx.x;
  int4 v = adj4[(size_t)blockIdx.x * 256 + t];
  unsigned n = (v.x > 0 ? 1u : 0u) | (v.y > 0 ? 2u : 0u) |
               (v.z > 0 ? 4u : 0u) | (v.w > 0 ? 8u : 0u);
  nib[t] = (unsigned char)n;
  __syncthreads();
  if (t < 16) {
    const unsigned char* p = &nib[t * 16];
    unsigned long long wv = 0;
#pragma unroll
    for (int i = 0; i < 16; ++i) wv |= (unsigned long long)p[i] << (4 * i);
    bits[(size_t)blockIdx.x * 16 + t] = wv;
  }
}

// ---------------- K2: Wh = h @ W via MFMA (h->fp16), dual store Wh/WhT ----------------
// Block 256 thr = 4 waves, 64 rows x 64 cols, K=128. Swizzled LDS (octet ^= row&7).
__global__ __launch_bounds__(256) void wh_kernel(const float* __restrict__ h,
                                                 const float* __restrict__ W,
                                                 _Float16* __restrict__ Wh16,
                                                 _Float16* __restrict__ WhT16) {
  __shared__ __align__(16) _Float16 hs[64 * 128];   // 16K, swizzled octets
  __shared__ __align__(16) _Float16 wt[64 * 128];   // 16K, W^T swizzled
  __shared__ __align__(16) _Float16 otile[64][72];  // 9K
  const int t = threadIdx.x;
  const int rowbase = blockIdx.x * 64;
  // stage h -> fp16: 64 rows x 16 octets, 4 octets/thread
#pragma unroll
  for (int i = 0; i < 4; ++i) {
    int e = i * 256 + t;
    int r = e >> 4, kb = e & 15;
    const float4v* src = (const float4v*)(h + (size_t)(rowbase + r) * F_ + kb * 8);
    float4v a = src[0], b = src[1];
    uint4 pk;
    pk.x = __builtin_bit_cast(unsigned, __builtin_amdgcn_cvt_pkrtz(a[0], a[1]));
    pk.y = __builtin_bit_cast(unsigned, __builtin_amdgcn_cvt_pkrtz(a[2], a[3]));
    pk.z = __builtin_bit_cast(unsigned, __builtin_amdgcn_cvt_pkrtz(b[0], b[1]));
    pk.w = __builtin_bit_cast(unsigned, __builtin_amdgcn_cvt_pkrtz(b[2], b[3]));
    *(uint4*)&hs[(r * 16 + (kb ^ (r & 7))) * 8] = pk;
  }
  // stage W^T fp16: W[f][c] -> wt[c][f] (swizzled); 2048 float4, 8/thread
#pragma unroll
  for (int k = 0; k < 8; ++k) {
    int i4 = t + k * 256;
    float4v v = ((const float4v*)W)[i4];
    int f = i4 >> 4, c4 = (i4 & 15) * 4;
    int oct = f >> 3, ki = f & 7;
#pragma unroll
    for (int j = 0; j < 4; ++j) {
      int c = c4 + j;
      wt[(c * 16 + (oct ^ (c & 7))) * 8 + ki] = (_Float16)v[j];
    }
  }
  __syncthreads();
  const int w = t >> 6, lane = t & 63;
  const int g = lane >> 4, c = lane & 15;
  const int r0 = w * 16;
  const int arow = r0 + c, aswz = arow & 7;
  half8 af[4];
#pragma unroll
  for (int kk = 0; kk < 4; ++kk)
    af[kk] = *(half8*)&hs[(arow * 16 + ((kk * 4 + g) ^ aswz)) * 8];
  float4v acc[4];
#pragma unroll
  for (int cb = 0; cb < 4; ++cb) {
    float4v z = (float4v){0.f, 0.f, 0.f, 0.f};
    const int bcol = cb * 16 + c, bswz = c & 7;
#pragma unroll
    for (int kk = 0; kk < 4; ++kk) {
      half8 bf = *(half8*)&wt[(bcol * 16 + ((kk * 4 + g) ^ bswz)) * 8];
      z = __builtin_amdgcn_mfma_f32_16x16x32_f16(af[kk], bf, z, 0, 0, 0);
    }
    acc[cb] = z;
  }
  __syncthreads();
  // C: lane(c,g) reg j -> row r0+g*4+j, col cb*16+c
#pragma unroll
  for (int cb = 0; cb < 4; ++cb)
#pragma unroll
    for (int j = 0; j < 4; ++j)
      otile[r0 + g * 4 + j][cb * 16 + c] = (_Float16)acc[cb][j];
  __syncthreads();
  const int rr = t >> 2, c0 = (t & 3) * 16;
  half8 w0 = *(half8*)&otile[rr][c0];
  half8 w1 = *(half8*)&otile[rr][c0 + 8];
  _Float16* dW = Wh16 + (size_t)(rowbase + rr) * D_ + c0;
  *(half8*)dW       = w0;
  *(half8*)(dW + 8) = w1;
  const int dl = t >> 2, k0t = (t & 3) * 16;
  half8 o0, o1;
#pragma unroll
  for (int i = 0; i < 8; ++i) o0[i] = otile[k0t + i][dl];
#pragma unroll
  for (int i = 0; i < 8; ++i) o1[i] = otile[k0t + 8 + i][dl];
  const int b = rowbase >> 12, n0 = rowbase & 4095;
  _Float16* dst = WhT16 + ((size_t)(b * D_ + dl)) * N_ + n0 + k0t;
  *(half8*)dst       = o0;
  *(half8*)(dst + 8) = o1;
}

// ---------------- K3: flash attention + ELU ----------------
// 512 thr = 8 waves: 4 q-chunks(16) x 2 KV-halves. K/V double-buffered LDS
// (XOR swizzle), 1 barrier/tile, peeled last tile (affine staging pointers).
// max3-tree tile max; alpha-skip rescale when running max doesn't grow.
__global__ __launch_bounds__(512, 4) void attn_kernel(
    const unsigned long long* __restrict__ bits,
    const _Float16* __restrict__ Wh,
    const _Float16* __restrict__ WhT,
    float* __restrict__ out) {
  __shared__ __align__(16) char lds[81920];
  const int tid  = threadIdx.x;
  const int w    = tid >> 6;
  const int lane = tid & 63;
  const int g    = lane >> 4;
  const int c    = lane & 15;
  const int qi   = w & 3;
  const int s    = w >> 2;
  const int bid  = blockIdx.x;
  const int b    = bid >> 6;
  const int q0b  = (bid & 63) * 64;
  const int q0w  = q0b + qi * 16;

  const _Float16* Whb  = Wh  + (size_t)b * N_ * D_;
  const _Float16* WhTb = WhT + (size_t)b * D_ * N_;
  char* Kbase = lds + s * 16384;
  char* Vbase = lds + 32768 + s * 16384;
  char* Pb    = lds + 65536 + w * 2048;

  const int e0  = (qi * 2 + 0) * 64 + lane;
  const int e1  = (qi * 2 + 1) * 64 + lane;
  const int r0e = e0 >> 3, s0e = (e0 & 7) ^ (r0e & 7);
  const int r1e = e1 >> 3, s1e = (e1 & 7) ^ (r1e & 7);

  half8 qf[2];
#pragma unroll
  for (int ds = 0; ds < 2; ++ds) {
    half8 v = *(const half8*)(Whb + (size_t)(q0w + c) * D_ + ds * 32 + g * 8);
    qf[ds] = v * (_Float16)0.18033688f;          // (1/8)*log2(e)
  }

  float4v o_acc[4];
#pragma unroll
  for (int d = 0; d < 4; ++d) o_acc[d] = (float4v){0.f, 0.f, 0.f, 0.f};
  float mrow = -1e30f, lrow = 0.f;

  const unsigned long long* bq = bits + (size_t)(q0w + c) * 64 + s * 32;

  // affine staging pointers (advance by constant stride per tile)
  const _Float16* pk0 = Whb + (size_t)(s * 2048 + r0e) * D_ + s0e * 8;
  const _Float16* pk1 = Whb + (size_t)(s * 2048 + r1e) * D_ + s1e * 8;
  const _Float16* pv0 = WhTb + (size_t)r0e * N_ + s * 2048 + s0e * 8;
  const _Float16* pv1 = WhTb + (size_t)r1e * N_ + s * 2048 + s1e * 8;

  // stage tile 0
  *(half8*)(Kbase + e0 * 16) = *(const half8*)pk0;
  *(half8*)(Kbase + e1 * 16) = *(const half8*)pk1;
  *(half8*)(Vbase + e0 * 16) = *(const half8*)pv0;
  *(half8*)(Vbase + e1 * 16) = *(const half8*)pv1;
  unsigned long long bw = bq[0];
  __syncthreads();

#define COMPUTE_TILE(CUR)                                                          \
  {                                                                                \
    const _Float16* Kc = (const _Float16*)(Kbase + (CUR));                         \
    const _Float16* Vc = (const _Float16*)(Vbase + (CUR));                         \
    float4v sac[4];                                                                \
    _Pragma("unroll")                                                              \
    for (int st = 0; st < 4; ++st) {                                               \
      const _Float16* kr = Kc + (st * 16 + c) * 64;                                \
      half8 kf0 = *(const half8*)(kr + ((g       ^ (c & 7)) * 8));                 \
      half8 kf1 = *(const half8*)(kr + (((g + 4) ^ (c & 7)) * 8));                 \
      float4v z = (float4v){0.f, 0.f, 0.f, 0.f};                                   \
      z = __builtin_amdgcn_mfma_f32_16x16x32_f16(kf0, qf[0], z, 0, 0, 0);          \
      z = __builtin_amdgcn_mfma_f32_16x16x32_f16(kf1, qf[1], z, 0, 0, 0);          \
      sac[st] = z;                                                                 \
    }                                                                              \
    _Pragma("unroll")                                                              \
    for (int st = 0; st < 4; ++st) {                                               \
      unsigned wb = (unsigned)(bw >> (st * 16 + g * 4));                           \
      _Pragma("unroll")                                                            \
      for (int j = 0; j < 4; ++j)                                                  \
        sac[st][j] = (wb & (1u << j)) ? sac[st][j] : -1e9f;                        \
    }                                                                              \
    float ta = fmaxf(fmaxf(sac[0][0], sac[0][1]), fmaxf(sac[0][2], sac[0][3]));    \
    float tb = fmaxf(fmaxf(sac[1][0], sac[1][1]), fmaxf(sac[1][2], sac[1][3]));    \
    float tc = fmaxf(fmaxf(sac[2][0], sac[2][1]), fmaxf(sac[2][2], sac[2][3]));    \
    float td = fmaxf(fmaxf(sac[3][0], sac[3][1]), fmaxf(sac[3][2], sac[3][3]));    \
    float tmax = fmaxf(fmaxf(ta, tb), fmaxf(tc, td));                              \
    tmax = fmaxf(tmax, __shfl_xor(tmax, 16));                                      \
    tmax = fmaxf(tmax, __shfl_xor(tmax, 32));                                      \
    if (__any(tmax > mrow)) {                                                      \
      float mnew  = fmaxf(mrow, tmax);                                             \
      float alpha = exp2f(mrow - mnew);                                            \
      mrow = mnew;                                                                 \
      lrow *= alpha;                                                               \
      _Pragma("unroll")                                                            \
      for (int j = 0; j < 4; ++j) {                                                \
        float aj = __shfl(alpha, (lane & 48) | (g * 4 + j));                       \
        _Pragma("unroll")                                                          \
        for (int d = 0; d < 4; ++d) o_acc[d][j] *= aj;                             \
      }                                                                            \
    }                                                                              \
    _Pragma("unroll")                                                              \
    for (int st = 0; st < 4; ++st) {                                               \
      float p0 = exp2f(sac[st][0] - mrow);                                         \
      float p1 = exp2f(sac[st][1] - mrow);                                         \
      float p2 = exp2f(sac[st][2] - mrow);                                         \
      float p3 = exp2f(sac[st][3] - mrow);                                         \
      lrow += (p0 + p1) + (p2 + p3);                                               \
      uint2 pr;                                                                    \
      pr.x = __builtin_bit_cast(unsigned, __builtin_amdgcn_cvt_pkrtz(p0, p1));     \
      pr.y = __builtin_bit_cast(unsigned, __builtin_amdgcn_cvt_pkrtz(p2, p3));     \
      const int cell = st * 2 + (g >> 1);                                          \
      *(uint2*)(Pb + (cell * 16 + c) * 16 + (g & 1) * 8) = pr;                     \
    }                                                                              \
    _Pragma("unroll")                                                              \
    for (int ks = 0; ks < 2; ++ks) {                                               \
      half8 afp = *(const half8*)(Pb + ((ks * 4 + g) * 16 + c) * 16);              \
      _Pragma("unroll")                                                            \
      for (int d = 0; d < 4; ++d) {                                                \
        half8 vf = *(const half8*)(Vc + (d * 16 + c) * 64 +                        \
                                   (((ks * 4 + g) ^ (c & 7)) * 8));                \
        o_acc[d] = __builtin_amdgcn_mfma_f32_16x16x32_f16(afp, vf, o_acc[d],       \
                                                          0, 0, 0);                \
      }                                                                            \
    }                                                                              \
  }

  int cur = 0;
#pragma unroll 2
  for (int t = 0; t < 31; ++t) {
    pk0 += 64 * D_; pk1 += 64 * D_; pv0 += 64; pv1 += 64;
    half8 ka = *(const half8*)pk0;
    half8 kb = *(const half8*)pk1;
    half8 va = *(const half8*)pv0;
    half8 vb = *(const half8*)pv1;
    unsigned long long bwn = bq[t + 1];

    COMPUTE_TILE(cur)

    const int nxt = cur ^ 8192;
    *(half8*)(Kbase + nxt + e0 * 16) = ka;
    *(half8*)(Kbase + nxt + e1 * 16) = kb;
    *(half8*)(Vbase + nxt + e0 * 16) = va;
    *(half8*)(Vbase + nxt + e1 * 16) = vb;
    __syncthreads();
    cur = nxt;
    bw = bwn;
  }
  COMPUTE_TILE(cur)
#undef COMPUTE_TILE

  // ---- epilogue: reduce l, merge the two KV-half partials, ELU, store ----
  lrow += __shfl_xor(lrow, 16);
  lrow += __shfl_xor(lrow, 32);
  __syncthreads();                               // all staging/P reads done
  float* Ob = (float*)lds;                       // [128][66] fp32
#pragma unroll
  for (int d = 0; d < 4; ++d)
#pragma unroll
    for (int j = 0; j < 4; ++j)
      Ob[(w * 16 + g * 4 + j) * 66 + d * 16 + c] = o_acc[d][j];
  float2* mlb = (float2*)(lds + 36864);
  if (g == 0) mlb[w * 16 + c] = make_float2(mrow, lrow);
  __syncthreads();

#pragma unroll
  for (int it = 0; it < 8; ++it) {
    int r   = w + it * 8;
    int col = lane;
    int qq = r >> 4, rl = r & 15;
    float2 ml0 = mlb[qq * 16 + rl];
    float2 ml1 = mlb[(qq + 4) * 16 + rl];
    float mm = fmaxf(ml0.x, ml1.x);
    float a0 = exp2f(ml0.x - mm);
    float a1 = exp2f(ml1.x - mm);
    float l  = a0 * ml0.y + a1 * ml1.y;
    float o  = a0 * Ob[(qq * 16 + rl) * 66 + col] + a1 * Ob[((qq + 4) * 16 + rl) * 66 + col];
    float x  = o / l;
    x = x > 0.f ? x : (__expf(x) - 1.f);
    out[((size_t)b * N_ + q0b + r) * D_ + col] = x;
  }
}

extern "C" void kernel_launch(void* const* d_in, const int* in_sizes, int n_in,
                              void* d_out, int out_size, void* d_ws, size_t ws_size,
                              hipStream_t stream) {
  const float* h = (const float*)d_in[0];
  const float* W = (const float*)d_in[1];
  const int* adj = (const int*)d_in[2];
  float* out = (float*)d_out;

  char* ws = (char*)d_ws;
  unsigned long long* bits = (unsigned long long*)ws;      // 2 MiB
  _Float16* Wh16  = (_Float16*)(ws + (2u << 20));          // 4 MiB
  _Float16* WhT16 = (_Float16*)(ws + (6u << 20));          // 4 MiB

  hipLaunchKernelGGL(pack_adj_kernel, dim3((N_ * N_) / 1024), dim3(256), 0, stream,
                     (const int4*)adj, bits);
  hipLaunchKernelGGL(wh_kernel,   dim3((B_ * N_) / 64), dim3(256), 0, stream, h, W, Wh16, WhT16);
  hipLaunchKernelGGL(attn_kernel, dim3(B_ * (N_ / 64)), dim3(512), 0, stream, bits, Wh16, WhT16, out);
}